// Round 3
// baseline (293.057 us; speedup 1.0000x reference)
//
#include <hip/hip_runtime.h>

// B=256 batches, N=128 neurons, E = 4N = 512. Out: ydot (B*E) | J (B*E*E).
#define BATCH 256
#define NN    128
#define EDIM  512

typedef float vf4 __attribute__((ext_vector_type(4)));

// ---------------------------------------------------------------------------
// Kernel 1: per-(batch, neuron) physics. Block = one batch, 512 threads:
// thread t -> (i = t>>2, jq = t&3); the 128-wide coupling dot is split 4-way
// and combined with shfl_xor.
// ---------------------------------------------------------------------------
__global__ __launch_bounds__(512) void hh_k1(
    const float* __restrict__ y,     const float* __restrict__ Ic,
    const float* __restrict__ C,     const float* __restrict__ g_Na,
    const float* __restrict__ E_Na,  const float* __restrict__ g_K,
    const float* __restrict__ E_K,   const float* __restrict__ g_L,
    const float* __restrict__ E_L,   const float* __restrict__ m_inf,
    const float* __restrict__ tau_m, const float* __restrict__ h_inf,
    const float* __restrict__ tau_h, const float* __restrict__ n_inf,
    const float* __restrict__ tau_n, const float* __restrict__ g_C,
    float* __restrict__ ydot_out,    float4* __restrict__ jtab,
    float* __restrict__ invC_out,    float* __restrict__ nitab)
{
    __shared__ float sInvC[NN];
    __shared__ float sW[NN];
    __shared__ float sRed[NN];
    __shared__ float sS;

    const int b  = blockIdx.x;
    const int t  = threadIdx.x;
    const int i  = t >> 2;
    const int jq = t & 3;

    if (t < NN) {
        const float ic = 1.0f / C[t];
        sInvC[t] = ic;
        sW[t] = y[(size_t)b * EDIM + 4 * t] * ic;   // V_j * invC_j
    }
    __syncthreads();

    // Partial dots over j = jq*32 .. jq*32+31 (8 float4 loads, independent)
    float rowS = 0.f, dotW = 0.f;
    const float4* grow = (const float4*)(g_C + (i << 7) + (jq << 5));
#pragma unroll
    for (int j4 = 0; j4 < 8; ++j4) {
        const float4 g = grow[j4];
        const int j = (jq << 5) + j4 * 4;
        rowS += g.x * sInvC[j] + g.y * sInvC[j + 1] + g.z * sInvC[j + 2] + g.w * sInvC[j + 3];
        dotW += g.x * sW[j]    + g.y * sW[j + 1]    + g.z * sW[j + 2]    + g.w * sW[j + 3];
    }
    rowS += __shfl_xor(rowS, 1);  rowS += __shfl_xor(rowS, 2);
    dotW += __shfl_xor(dotW, 1);  dotW += __shfl_xor(dotW, 2);

    if (jq == 0) sRed[i] = rowS;
    __syncthreads();
    if (t < 64) {   // S = sum_i rowS[i]  (reference: jnp.sum(gC_over_C))
        float v = sRed[t] + sRed[t + 64];
        v += __shfl_xor(v, 1);  v += __shfl_xor(v, 2);  v += __shfl_xor(v, 4);
        v += __shfl_xor(v, 8);  v += __shfl_xor(v, 16); v += __shfl_xor(v, 32);
        if (t == 0) sS = v;
    }
    __syncthreads();

    if (jq == 0) {
        const float S = sS;
        const float4 yv = ((const float4*)(y + (size_t)b * EDIM))[i];
        const float V = yv.x, m = yv.y, h = yv.z, n = yv.w;
        const float invC = sInvC[i];
        const float dV = V * rowS - dotW;

        const float m2 = m * m, m3 = m2 * m;
        const float n2 = n * n, n3 = n2 * n, n4 = n3 * n;
        const float gna = g_Na[i], ena = E_Na[i];
        const float gk  = g_K[i],  ek  = E_K[i];
        const float gl  = g_L[i],  el  = E_L[i];

        const float Vdot = invC * (-gna * m3 * h * (V - ena)
                                   - gk * n4 * (V - ek)
                                   - gl * (V - el)
                                   + Ic[b]) + dV;
        const float itm = 1.0f / tau_m[i];
        const float ith = 1.0f / tau_h[i];
        const float itn = 1.0f / tau_n[i];

        ((float4*)(ydot_out + (size_t)b * EDIM))[i] =
            make_float4(Vdot, (m_inf[i] - m) * itm, (h_inf[i] - h) * ith,
                        (n_inf[i] - n) * itn);

        const float jvv = invC * (-gl - gna * h * m3 - gk * n4) + S;
        const float jvm = -invC * (3.0f * gna * h * m2 * (V - ena));
        const float jvh = -invC * (gna * m3 * (V - ena));
        const float jvn = -invC * (4.0f * gk * n3 * (V - ek));
        jtab[(b << 7) + i] = make_float4(jvv, jvm, jvh, jvn);

        if (b == 0) {
            invC_out[i]       = invC;
            nitab[i]          = -itm;
            nitab[NN + i]     = -ith;
            nitab[2 * NN + i] = -itn;
        }
    }
}

// ---------------------------------------------------------------------------
// Kernel 2: fill J. One wave owns one aligned 8 KB block = the 4 rows
// (a=0..3) of one (b,i). 8 dwordx4 store instructions per wave, each 1 KB
// fully contiguous; `a` is uniform per instruction. One g_C row load
// (2x 256 B, L2-resident) per 8 KB written.
// ---------------------------------------------------------------------------
__global__ __launch_bounds__(256) void hh_k2(
    const float4* __restrict__ jtab, const float* __restrict__ invC,
    const float* __restrict__ nitab, const float* __restrict__ g_C,
    vf4* __restrict__ J)
{
    const int lane   = threadIdx.x & 63;
    const unsigned w = blockIdx.x * 4u + (threadIdx.x >> 6);  // wave id [0,32768)
    const int b = w >> 7;
    const int i = w & 127;

    vf4* __restrict__ Jblk = J + (size_t)w * 512;   // rows 4i..4i+3 of batch b

    const float4 jv = jtab[(b << 7) + i];           // broadcast, L1
    const float nit1 = nitab[i];
    const float nit2 = nitab[NN + i];
    const float nit3 = nitab[2 * NN + i];

    // a = 0 row (dense): float4 columns 0..127, two half-row instructions
#pragma unroll
    for (int half = 0; half < 2; ++half) {
        const int c4 = half * 64 + lane;
        float v0 = -g_C[(i << 7) + c4] * invC[c4];
        float v1 = 0.f, v2 = 0.f, v3 = 0.f;
        if (c4 == i) { v0 += jv.x; v1 = jv.y; v2 = jv.z; v3 = jv.w; }
        const vf4 v = {v0, v1, v2, v3};
        Jblk[c4] = v;
    }
    // a = 1..3 rows: zero except single diagonal element
#pragma unroll
    for (int half = 0; half < 2; ++half) {
        const int c4 = half * 64 + lane;
        vf4 v1 = {0.f, 0.f, 0.f, 0.f};
        vf4 v2 = v1, v3 = v1;
        if (c4 == i) { v1.y = nit1; v2.z = nit2; v3.w = nit3; }
        Jblk[128 + c4] = v1;
        Jblk[256 + c4] = v2;
        Jblk[384 + c4] = v3;
    }
}

extern "C" void kernel_launch(void* const* d_in, const int* in_sizes, int n_in,
                              void* d_out, int out_size, void* d_ws, size_t ws_size,
                              hipStream_t stream) {
    const float* y     = (const float*)d_in[0];
    const float* Ic    = (const float*)d_in[1];
    const float* C     = (const float*)d_in[2];
    const float* g_Na  = (const float*)d_in[3];
    const float* E_Na  = (const float*)d_in[4];
    const float* g_K   = (const float*)d_in[5];
    const float* E_K   = (const float*)d_in[6];
    const float* g_L   = (const float*)d_in[7];
    const float* E_L   = (const float*)d_in[8];
    const float* m_inf = (const float*)d_in[9];
    const float* tau_m = (const float*)d_in[10];
    const float* h_inf = (const float*)d_in[11];
    const float* tau_h = (const float*)d_in[12];
    const float* n_inf = (const float*)d_in[13];
    const float* tau_n = (const float*)d_in[14];
    const float* g_C   = (const float*)d_in[15];

    float* ydot = (float*)d_out;
    vf4*   J    = (vf4*)((float*)d_out + (size_t)BATCH * EDIM);

    float4* jtab = (float4*)d_ws;
    float*  invC = (float*)((char*)d_ws + (size_t)BATCH * NN * sizeof(float4));
    float*  nit  = invC + NN;

    hh_k1<<<BATCH, 512, 0, stream>>>(y, Ic, C, g_Na, E_Na, g_K, E_K, g_L, E_L,
                                     m_inf, tau_m, h_inf, tau_h, n_inf, tau_n,
                                     g_C, ydot, jtab, invC, nit);

    // 32768 waves / 4 waves-per-block
    hh_k2<<<8192, 256, 0, stream>>>(jtab, invC, nit, g_C, J);
}